// Round 8
// baseline (178.707 us; speedup 1.0000x reference)
//
#include <hip/hip_runtime.h>
#include <hip/hip_bf16.h>

// MixtureExperts as dense GEMM: out[2048,16384] = G[2048,64] @ Wt[16384,64]^T
//   G[b,e] = count_k(idx[b,k]==e) * sel[b,e]   (exact duplicate handling)
//
// Round-8 fix vs round-7: operand roles swapped so the D-fragment's
// col=lane&15 is a CONTIGUOUS output column -> dense 64B-line stores.
//   A lane l: A[m=l&15][k=8*(l>>4)+j]  -> G[b][e]  ([m][k] storage, natural)
//   B lane l: B[k=8*(l>>4)+j][n=l&15]  -> Wt[n][e] ([n][k] storage, natural)
//   D lane l reg r: D[row=4*(l>>4)+r][col=l&15]  (row=batch, col=n)
// Roofline: 128 MiB fp32 output writes ~= 21 us @ 6.3 TB/s.

constexpr int BS = 2048, NE = 64, TK = 8;
constexpr int PD = 32 * 512;   // 16384

typedef float          f32x4 __attribute__((ext_vector_type(4)));
typedef short          s16x8 __attribute__((ext_vector_type(8)));
typedef unsigned short u16x4 __attribute__((ext_vector_type(4)));
typedef unsigned short u16x8 __attribute__((ext_vector_type(8)));

__device__ __forceinline__ unsigned short f2bf(float f) {
    __hip_bfloat16 h = __float2bfloat16(f);   // library RNE
    return __builtin_bit_cast(unsigned short, h);
}

// --- kernel 1: dense gate G[b][e] (bf16). One wave per row, lane = expert. ---
__global__ __launch_bounds__(256) void build_gate(
    const float* __restrict__ sel, const int* __restrict__ idx,
    unsigned short* __restrict__ G)
{
    const int b = blockIdx.x * 4 + (threadIdx.x >> 6);
    const int e = threadIdx.x & 63;
    int cnt = 0;
#pragma unroll
    for (int k = 0; k < TK; ++k) cnt += (idx[b * TK + k] == e) ? 1 : 0;
    G[b * NE + e] = f2bf((float)cnt * sel[b * NE + e]);
}

// --- kernel 2: Wt[n][e] = bf16(W[e][n]) via LDS transpose, 128-col tiles ---
__global__ __launch_bounds__(256) void build_wt(
    const float* __restrict__ W, unsigned short* __restrict__ Wt)
{
    __shared__ unsigned short lds[NE][128];   // 16 KiB
    const int n0 = blockIdx.x * 128;
    const int t  = threadIdx.x;

    for (int i = t; i < NE * 32; i += 256) {          // 64 experts x 32 f32x4
        const int e = i >> 5, n4 = i & 31;
        const f32x4 w = *reinterpret_cast<const f32x4*>(W + (size_t)e * PD + n0 + n4 * 4);
        u16x4 r;
#pragma unroll
        for (int j = 0; j < 4; ++j) r[j] = f2bf(w[j]);
        *reinterpret_cast<u16x4*>(&lds[e][n4 * 4]) = r;
    }
    __syncthreads();

    if (t < 128) {                                     // thread t -> row n0+t
        unsigned short* dst = Wt + (size_t)(n0 + t) * NE;
#pragma unroll
        for (int j = 0; j < 8; ++j) {
            u16x8 v;
#pragma unroll
            for (int jj = 0; jj < 8; ++jj) v[jj] = lds[j * 8 + jj][t];
            *reinterpret_cast<u16x8*>(dst + j * 8) = v;
        }
    }
}

// --- kernel 3: GEMM, no LDS, no barriers; coalesced dword stores ---
__global__ __launch_bounds__(256) void gemm_moe(
    const unsigned short* __restrict__ G,    // [BS][NE] bf16
    const unsigned short* __restrict__ Wt,   // [PD][NE] bf16
    float* __restrict__ out)                 // [BS][PD]
{
    const int t   = threadIdx.x;
    const int w   = t >> 6, l = t & 63;
    const int col = l & 15, q = l >> 4;

    const int bt  = blockIdx.x & 31;          // 32 batch-tiles of 64 rows
    const int nb  = blockIdx.x >> 5;          // 128 n-tiles of 128 cols
    const int mb  = bt * 64 + w * 16;         // this wave's 16 batch rows
    const int nt0 = nb * 128;

    const short* Gs  = reinterpret_cast<const short*>(G);
    const short* Wts = reinterpret_cast<const short*>(Wt);

    // A-operand fragments (gate rows, m = batch): loaded once, reused 8x
    const s16x8 ga0 = *reinterpret_cast<const s16x8*>(Gs + (mb + col) * NE + 8 * q);
    const s16x8 ga1 = *reinterpret_cast<const s16x8*>(Gs + (mb + col) * NE + 32 + 8 * q);

#pragma unroll
    for (int s = 0; s < 8; ++s) {
        const int n0 = nt0 + s * 16;
        const s16x8 wb0 = *reinterpret_cast<const s16x8*>(
            Wts + (size_t)(n0 + col) * NE + 8 * q);
        const s16x8 wb1 = *reinterpret_cast<const s16x8*>(
            Wts + (size_t)(n0 + col) * NE + 32 + 8 * q);
        f32x4 c = {0.f, 0.f, 0.f, 0.f};
        c = __builtin_amdgcn_mfma_f32_16x16x32_bf16(ga0, wb0, c, 0, 0, 0);
        c = __builtin_amdgcn_mfma_f32_16x16x32_bf16(ga1, wb1, c, 0, 0, 0);
        // D[row=4q+r][col]: row = batch (mb+4q+r), col = n (n0+col).
        // 16 consecutive lanes of each quarter-wave -> one dense 64B line.
#pragma unroll
        for (int r = 0; r < 4; ++r)
            __builtin_nontemporal_store(c[r],
                out + (size_t)(mb + 4 * q + r) * PD + n0 + col);
    }
}

// --- fallback if ws too small: round-2 fp32 gather ---
__global__ __launch_bounds__(256) void moe_mix_f32(
    const float* __restrict__ sel, const int* __restrict__ idx,
    const float* __restrict__ W, float* __restrict__ out)
{
    const int b = blockIdx.x, t = threadIdx.x;
    int e[TK]; float s[TK];
#pragma unroll
    for (int k = 0; k < TK; ++k) {
        e[k] = idx[b * TK + k];
        s[k] = sel[b * NE + e[k]];
    }
    const f32x4* W4 = reinterpret_cast<const f32x4*>(W);
    f32x4*       O4 = reinterpret_cast<f32x4*>(out) + (size_t)b * (PD / 4);
#pragma unroll 2
    for (int j = 0; j < (PD / 4) / 256; ++j) {
        const int f4 = t + j * 256;
        f32x4 acc = (f32x4)(0.f);
#pragma unroll
        for (int k = 0; k < TK; ++k)
            acc += s[k] * W4[(size_t)e[k] * (PD / 4) + f4];
        __builtin_nontemporal_store(acc, &O4[f4]);
    }
}

extern "C" void kernel_launch(void* const* d_in, const int* in_sizes, int n_in,
                              void* d_out, int out_size, void* d_ws, size_t ws_size,
                              hipStream_t stream) {
    const float* sel = (const float*)d_in[0];
    const int*   idx = (const int*)d_in[1];
    const float* W   = (const float*)d_in[2];
    float*       out = (float*)d_out;

    const size_t needG  = (size_t)BS * NE * sizeof(unsigned short);  // 256 KiB
    const size_t needWt = (size_t)PD * NE * sizeof(unsigned short);  // 2 MiB

    if (ws_size >= needG + needWt) {
        unsigned short* G  = (unsigned short*)d_ws;
        unsigned short* Wt = (unsigned short*)d_ws + (size_t)BS * NE;
        build_gate<<<dim3(BS / 4), dim3(256), 0, stream>>>(sel, idx, G);
        build_wt  <<<dim3(PD / 128), dim3(256), 0, stream>>>(W, Wt);
        gemm_moe  <<<dim3(32 * 128), dim3(256), 0, stream>>>(G, Wt, out);
    } else {
        moe_mix_f32<<<dim3(BS), dim3(256), 0, stream>>>(sel, idx, W, out);
    }
}

// Round 10
// 160.875 us; speedup vs baseline: 1.1108x; 1.1108x over previous
//
#include <hip/hip_runtime.h>
#include <hip/hip_bf16.h>

// MixtureExperts: out[b,p,d] = sum_k sel[b, idx[b,k]] * W[idx[b,k], p, d]
// BS=2048, NE=64, TK=8, P=32, D=512
//
// Round 9: barrier-free global gather with bf16 weights.
//   k1: W fp32 (4 MiB) -> Wb bf16 (2 MiB) in d_ws   [r6-proven convert code]
//   k2: per batch row, gather 8 expert rows from Wb (L2-resident working set),
//       fp32 accumulate, 32 B/lane non-temporal full-line stores.
// No LDS / no barriers -> 32 waves/CU; read (L2 ~15us) and store (HBM ~21us)
// streams overlap across waves. Roofline: ~21.5 us stores + ~2 us convert.

constexpr int BS = 2048, NE = 64, TK = 8;
constexpr int PD  = 32 * 512;   // 16384 floats per expert / out row
constexpr int PD8 = PD / 8;     // 2048 chunks of 8 bf16

typedef float          f32x4 __attribute__((ext_vector_type(4)));
typedef unsigned short u16x4 __attribute__((ext_vector_type(4)));
typedef unsigned short u16x8 __attribute__((ext_vector_type(8)));

__device__ __forceinline__ unsigned short f2bf(float f) {
    __hip_bfloat16 h = __float2bfloat16(f);   // library RNE
    return __builtin_bit_cast(unsigned short, h);
}
__device__ __forceinline__ float bf2f(unsigned short u) {
    return __builtin_bit_cast(float, (unsigned)u << 16);
}

// --- kernel 1: W -> bf16 ---
__global__ __launch_bounds__(256) void w_to_bf16(
    const float* __restrict__ W, unsigned short* __restrict__ Wb)
{
    const int i = (blockIdx.x * 256 + threadIdx.x) * 4;
    const f32x4 w = *reinterpret_cast<const f32x4*>(W + i);
    u16x4 r;
#pragma unroll
    for (int j = 0; j < 4; ++j) r[j] = f2bf(w[j]);
    *reinterpret_cast<u16x4*>(Wb + i) = r;
}

// --- kernel 2: gather + mix, no LDS, no barriers ---
__global__ __launch_bounds__(256) void moe_gather(
    const float*          __restrict__ sel,  // [BS, NE]
    const int*            __restrict__ idx,  // [BS, TK]
    const unsigned short* __restrict__ Wb,   // [NE, PD] bf16
    float*                __restrict__ out)  // [BS, PD]
{
    const int b = blockIdx.x;
    const int t = threadIdx.x;

    // routing metadata: vector idx load + score gather (wave-uniform)
    const int4 e01 = reinterpret_cast<const int4*>(idx + b * TK)[0];
    const int4 e23 = reinterpret_cast<const int4*>(idx + b * TK)[1];
    const int e[TK] = {e01.x, e01.y, e01.z, e01.w, e23.x, e23.y, e23.z, e23.w};
    float s[TK];
#pragma unroll
    for (int k = 0; k < TK; ++k) s[k] = sel[b * NE + e[k]];

    const u16x8* __restrict__ W8 = reinterpret_cast<const u16x8*>(Wb);
    float* __restrict__ Ob = out + (size_t)b * PD;

#pragma unroll 2
    for (int j = 0; j < PD8 / 256; ++j) {     // 8 iterations
        const int g8 = t + j * 256;           // chunk of 8 cols
        f32x4 a0 = (f32x4)(0.f);
        f32x4 a1 = (f32x4)(0.f);
#pragma unroll
        for (int k = 0; k < TK; ++k) {
            const u16x8 w = W8[e[k] * PD8 + g8];
#pragma unroll
            for (int m = 0; m < 4; ++m) {
                a0[m] += s[k] * bf2f(w[m]);
                a1[m] += s[k] * bf2f(w[m + 4]);
            }
        }
        f32x4* op = reinterpret_cast<f32x4*>(Ob + (size_t)g8 * 8);
        __builtin_nontemporal_store(a0, op);
        __builtin_nontemporal_store(a1, op + 1);
    }
}

// --- fallback (ws too small): round-2 fp32 gather ---
__global__ __launch_bounds__(256) void moe_mix_f32(
    const float* __restrict__ sel, const int* __restrict__ idx,
    const float* __restrict__ W, float* __restrict__ out)
{
    const int b = blockIdx.x, t = threadIdx.x;
    int e[TK]; float s[TK];
#pragma unroll
    for (int k = 0; k < TK; ++k) {
        e[k] = idx[b * TK + k];
        s[k] = sel[b * NE + e[k]];
    }
    const f32x4* W4 = reinterpret_cast<const f32x4*>(W);
    f32x4*       O4 = reinterpret_cast<f32x4*>(out) + (size_t)b * (PD / 4);
#pragma unroll 2
    for (int j = 0; j < (PD / 4) / 256; ++j) {
        const int f4 = t + j * 256;
        f32x4 acc = (f32x4)(0.f);
#pragma unroll
        for (int k = 0; k < TK; ++k)
            acc += s[k] * W4[(size_t)e[k] * (PD / 4) + f4];
        __builtin_nontemporal_store(acc, &O4[f4]);
    }
}

extern "C" void kernel_launch(void* const* d_in, const int* in_sizes, int n_in,
                              void* d_out, int out_size, void* d_ws, size_t ws_size,
                              hipStream_t stream) {
    const float* sel = (const float*)d_in[0];
    const int*   idx = (const int*)d_in[1];
    const float* W   = (const float*)d_in[2];
    float*       out = (float*)d_out;

    const size_t need = (size_t)NE * PD * sizeof(unsigned short);  // 2 MiB
    if (ws_size >= need) {
        unsigned short* Wb = (unsigned short*)d_ws;
        w_to_bf16 <<<dim3(NE * PD / (256 * 4)), dim3(256), 0, stream>>>(W, Wb);
        moe_gather<<<dim3(BS), dim3(256), 0, stream>>>(sel, idx, Wb, out);
    } else {
        moe_mix_f32<<<dim3(BS), dim3(256), 0, stream>>>(sel, idx, W, out);
    }
}

// Round 12
// 160.636 us; speedup vs baseline: 1.1125x; 1.0015x over previous
//
#include <hip/hip_runtime.h>
#include <hip/hip_bf16.h>

// MixtureExperts: out[b,p,d] = sum_k sel[b, idx[b,k]] * W[idx[b,k], p, d]
// BS=2048, NE=64, TK=8, P=32, D=512
//
// Round 11: r10 structure + depth-1 software pipeline in the gather kernel.
// Issue order per iteration: loads(j+1) -> compute(j) -> stores(j), so the
// compiler's counted s_waitcnt for loads(j+1) (vmcnt(10)) never drains the
// store stream (stores share vmcnt with loads, in-order retirement).
// Roofline: ~21.5 us stores + ~2 us convert, fixed harness fills ~107 us.

constexpr int BS = 2048, NE = 64, TK = 8;
constexpr int PD  = 32 * 512;   // 16384 floats per expert / out row
constexpr int PD8 = PD / 8;     // 2048 chunks of 8 bf16

typedef float          f32x4 __attribute__((ext_vector_type(4)));
typedef unsigned short u16x4 __attribute__((ext_vector_type(4)));
typedef unsigned short u16x8 __attribute__((ext_vector_type(8)));

__device__ __forceinline__ unsigned short f2bf(float f) {
    __hip_bfloat16 h = __float2bfloat16(f);   // library RNE
    return __builtin_bit_cast(unsigned short, h);
}
__device__ __forceinline__ float bf2f(unsigned short u) {
    return __builtin_bit_cast(float, (unsigned)u << 16);
}

// --- kernel 1: W -> bf16 (2 MiB into d_ws) ---
__global__ __launch_bounds__(256) void w_to_bf16(
    const float* __restrict__ W, unsigned short* __restrict__ Wb)
{
    const int i = (blockIdx.x * 256 + threadIdx.x) * 4;
    const f32x4 w = *reinterpret_cast<const f32x4*>(W + i);
    u16x4 r;
#pragma unroll
    for (int j = 0; j < 4; ++j) r[j] = f2bf(w[j]);
    *reinterpret_cast<u16x4*>(Wb + i) = r;
}

// --- kernel 2: gather + mix, depth-1 pipelined, no LDS/barriers ---
__global__ __launch_bounds__(256) void moe_gather(
    const float*          __restrict__ sel,  // [BS, NE]
    const int*            __restrict__ idx,  // [BS, TK]
    const unsigned short* __restrict__ Wb,   // [NE, PD] bf16
    float*                __restrict__ out)  // [BS, PD]
{
    const int b = blockIdx.x;
    const int t = threadIdx.x;

    const int4 e01 = reinterpret_cast<const int4*>(idx + b * TK)[0];
    const int4 e23 = reinterpret_cast<const int4*>(idx + b * TK)[1];
    const int e[TK] = {e01.x, e01.y, e01.z, e01.w, e23.x, e23.y, e23.z, e23.w};
    int   off[TK];
    float s[TK];
#pragma unroll
    for (int k = 0; k < TK; ++k) {
        off[k] = e[k] * PD8;                 // row base in u16x8 units
        s[k]   = sel[b * NE + e[k]];
    }

    const u16x8* __restrict__ W8 = reinterpret_cast<const u16x8*>(Wb);
    float* __restrict__ Ob = out + (size_t)b * PD;

    // prologue: loads for iteration 0
    u16x8 w[TK];
#pragma unroll
    for (int k = 0; k < TK; ++k) w[k] = W8[off[k] + t];

#pragma unroll
    for (int j = 0; j < PD8 / 256; ++j) {    // 8 iterations, fully unrolled
        u16x8 wn[TK];
        if (j < PD8 / 256 - 1) {             // static guard (unrolled)
#pragma unroll
            for (int k = 0; k < TK; ++k)
                wn[k] = W8[off[k] + t + (j + 1) * 256];
        }

        f32x4 a0 = (f32x4)(0.f);
        f32x4 a1 = (f32x4)(0.f);
#pragma unroll
        for (int k = 0; k < TK; ++k) {
#pragma unroll
            for (int m = 0; m < 4; ++m) {
                a0[m] += s[k] * bf2f(w[k][m]);
                a1[m] += s[k] * bf2f(w[k][m + 4]);
            }
        }
        f32x4* op = reinterpret_cast<f32x4*>(Ob + (size_t)(t + j * 256) * 8);
        __builtin_nontemporal_store(a0, op);
        __builtin_nontemporal_store(a1, op + 1);

        if (j < PD8 / 256 - 1) {
#pragma unroll
            for (int k = 0; k < TK; ++k) w[k] = wn[k];   // register rotation
        }
    }
}

// --- fallback (ws too small): round-2 fp32 gather ---
__global__ __launch_bounds__(256) void moe_mix_f32(
    const float* __restrict__ sel, const int* __restrict__ idx,
    const float* __restrict__ W, float* __restrict__ out)
{
    const int b = blockIdx.x, t = threadIdx.x;
    int e[TK]; float s[TK];
#pragma unroll
    for (int k = 0; k < TK; ++k) {
        e[k] = idx[b * TK + k];
        s[k] = sel[b * NE + e[k]];
    }
    const f32x4* W4 = reinterpret_cast<const f32x4*>(W);
    f32x4*       O4 = reinterpret_cast<f32x4*>(out) + (size_t)b * (PD / 4);
#pragma unroll 2
    for (int j = 0; j < (PD / 4) / 256; ++j) {
        const int f4 = t + j * 256;
        f32x4 acc = (f32x4)(0.f);
#pragma unroll
        for (int k = 0; k < TK; ++k)
            acc += s[k] * W4[(size_t)e[k] * (PD / 4) + f4];
        __builtin_nontemporal_store(acc, &O4[f4]);
    }
}

extern "C" void kernel_launch(void* const* d_in, const int* in_sizes, int n_in,
                              void* d_out, int out_size, void* d_ws, size_t ws_size,
                              hipStream_t stream) {
    const float* sel = (const float*)d_in[0];
    const int*   idx = (const int*)d_in[1];
    const float* W   = (const float*)d_in[2];
    float*       out = (float*)d_out;

    const size_t need = (size_t)NE * PD * sizeof(unsigned short);  // 2 MiB
    if (ws_size >= need) {
        unsigned short* Wb = (unsigned short*)d_ws;
        w_to_bf16 <<<dim3(NE * PD / (256 * 4)), dim3(256), 0, stream>>>(W, Wb);
        moe_gather<<<dim3(BS), dim3(256), 0, stream>>>(sel, idx, Wb, out);
    } else {
        moe_mix_f32<<<dim3(BS), dim3(256), 0, stream>>>(sel, idx, W, out);
    }
}